// Round 2
// baseline (238.213 us; speedup 1.0000x reference)
//
#include <hip/hip_runtime.h>
#include <cstdint>

#define NB 64
#define NC 512
#define NDIM 512
#define NOUT 512
#define NGROUPS 32
#define CPG 16
#define EPSV 1e-5f
#define SM_SCALE 0.044194173824159216f

typedef unsigned short u16;
typedef __attribute__((ext_vector_type(8))) short short8;
typedef __attribute__((ext_vector_type(4))) float f32x4;

__device__ __forceinline__ u16 f2bf(float f) {
  union { float f; uint32_t u; } v; v.f = f;
  return (u16)((v.u + 0x7FFFu + ((v.u >> 16) & 1u)) >> 16);
}

__device__ __forceinline__ void gload_lds16(const void* g, void* l) {
  __builtin_amdgcn_global_load_lds((const __attribute__((address_space(1))) void*)g,
                                   (__attribute__((address_space(3))) void*)l, 16, 0, 0);
}

// ---------------- GroupNorm stats: one block per (b, group) ----------------
__global__ __launch_bounds__(256) void gn_stats_k(const float* __restrict__ x,
                                                  float* __restrict__ stats) {
  const int bg = blockIdx.x;                    // 0..2047
  const float* p = x + (size_t)bg * (CPG * NDIM);
  float s = 0.f, ss = 0.f;
  for (int i = threadIdx.x * 4; i < CPG * NDIM; i += 256 * 4) {
    float4 v = *reinterpret_cast<const float4*>(p + i);
    s += v.x + v.y + v.z + v.w;
    ss += v.x * v.x + v.y * v.y + v.z * v.z + v.w * v.w;
  }
  for (int off = 32; off; off >>= 1) { s += __shfl_xor(s, off); ss += __shfl_xor(ss, off); }
  __shared__ float ls[4], lss[4];
  const int w = threadIdx.x >> 6;
  if ((threadIdx.x & 63) == 0) { ls[w] = s; lss[w] = ss; }
  __syncthreads();
  if (threadIdx.x == 0) {
    s = ls[0] + ls[1] + ls[2] + ls[3];
    ss = lss[0] + lss[1] + lss[2] + lss[3];
    const float inv_n = 1.0f / (CPG * NDIM);
    float mean = s * inv_n;
    float var = ss * inv_n - mean * mean;
    stats[2 * bg] = mean;
    stats[2 * bg + 1] = rsqrtf(var + EPSV);
  }
}

// ---------------- Apply GN affine, write bf16 xn ----------------
__global__ __launch_bounds__(256) void gn_apply_k(const float* __restrict__ x,
                                                  const float* __restrict__ stats,
                                                  const float* __restrict__ gw,
                                                  const float* __restrict__ gb,
                                                  u16* __restrict__ xn) {
  size_t t = (size_t)blockIdx.x * 256 + threadIdx.x;
  size_t base = t * 8;
  int c = (int)((base / NDIM) % NC);
  int bg = (int)(base / ((size_t)CPG * NDIM));
  float mean = stats[2 * bg], rstd = stats[2 * bg + 1];
  float sc = gw[c] * rstd;
  float sh = gb[c] - mean * sc;
  float4 v0 = *reinterpret_cast<const float4*>(x + base);
  float4 v1 = *reinterpret_cast<const float4*>(x + base + 4);
  u16 o[8];
  o[0] = f2bf(v0.x * sc + sh); o[1] = f2bf(v0.y * sc + sh);
  o[2] = f2bf(v0.z * sc + sh); o[3] = f2bf(v0.w * sc + sh);
  o[4] = f2bf(v1.x * sc + sh); o[5] = f2bf(v1.y * sc + sh);
  o[6] = f2bf(v1.z * sc + sh); o[7] = f2bf(v1.w * sc + sh);
  *reinterpret_cast<uint4*>(xn + base) = *reinterpret_cast<const uint4*>(o);
}

// ---------------- fp32 -> bf16 cast (weights) ----------------
__global__ __launch_bounds__(256) void cast_bf_k(const float* __restrict__ in,
                                                 u16* __restrict__ out) {
  size_t base = ((size_t)blockIdx.x * 256 + threadIdx.x) * 8;
  float4 v0 = *reinterpret_cast<const float4*>(in + base);
  float4 v1 = *reinterpret_cast<const float4*>(in + base + 4);
  u16 o[8];
  o[0] = f2bf(v0.x); o[1] = f2bf(v0.y); o[2] = f2bf(v0.z); o[3] = f2bf(v0.w);
  o[4] = f2bf(v1.x); o[5] = f2bf(v1.y); o[6] = f2bf(v1.z); o[7] = f2bf(v1.w);
  *reinterpret_cast<uint4*>(out + base) = *reinterpret_cast<const uint4*>(o);
}

// ---------------- Batched GEMM: out[m,n] = sum_k A[m,k]*B[n,k] (+bias) ------
// OUT_MODE: 0 = bf16 out, bias[col]; 1 = bf16 out, bias[row]; 2 = f32 out, no bias
template <int OUT_MODE>
__global__ __launch_bounds__(256) void gemm_abt_k(const u16* __restrict__ A, size_t sA,
                                                  const u16* __restrict__ Bm, size_t sB,
                                                  const float* __restrict__ bias,
                                                  void* __restrict__ out, size_t sO) {
  __shared__ u16 As[128 * 32];
  __shared__ u16 Bs[128 * 32];
  const int b = blockIdx.y;
  const u16* Ab = A + (size_t)b * sA;
  const u16* Bb = Bm + (size_t)b * sB;
  const int tile = blockIdx.x;                    // 0..15
  const int tm = (tile >> 2) * 128, tn = (tile & 3) * 128;
  const int tid = threadIdx.x;
  const int w = tid >> 6, lane = tid & 63;
  const int wr = (w >> 1) * 64, wc = (w & 1) * 64;

  f32x4 acc[4][4] = {};
  const int srow = lane >> 2;                     // staging row within 16-row chunk
  const int scol = (lane & 3) * 8;                // staging col (elements)

  for (int k0 = 0; k0 < 512; k0 += 32) {
#pragma unroll
    for (int i = 0; i < 2; ++i) {
      const int ch = w + i * 4;                   // 0..7 chunk of 1KB
      gload_lds16(Ab + (size_t)(tm + ch * 16 + srow) * 512 + k0 + scol, As + ch * 512);
      gload_lds16(Bb + (size_t)(tn + ch * 16 + srow) * 512 + k0 + scol, Bs + ch * 512);
    }
    asm volatile("s_waitcnt vmcnt(0)" ::: "memory");
    __syncthreads();
    const int frow = lane & 15;
    const int fk = (lane >> 4) * 8;
    short8 af[4], bf[4];
#pragma unroll
    for (int i = 0; i < 4; ++i) {
      af[i] = *reinterpret_cast<const short8*>(&As[(wr + i * 16 + frow) * 32 + fk]);
      bf[i] = *reinterpret_cast<const short8*>(&Bs[(wc + i * 16 + frow) * 32 + fk]);
    }
#pragma unroll
    for (int mi = 0; mi < 4; ++mi)
#pragma unroll
      for (int ni = 0; ni < 4; ++ni)
        acc[mi][ni] = __builtin_amdgcn_mfma_f32_16x16x32_bf16(af[mi], bf[ni], acc[mi][ni], 0, 0, 0);
    __syncthreads();
  }

  const int col0 = lane & 15, row0 = (lane >> 4) * 4;
#pragma unroll
  for (int mi = 0; mi < 4; ++mi) {
#pragma unroll
    for (int ni = 0; ni < 4; ++ni) {
      const int gc = tn + wc + ni * 16 + col0;
#pragma unroll
      for (int r = 0; r < 4; ++r) {
        const int gr = tm + wr + mi * 16 + row0 + r;
        float v = acc[mi][ni][r];
        if (OUT_MODE == 0) v += bias[gc];
        if (OUT_MODE == 1) v += bias[gr];
        if (OUT_MODE == 2) {
          ((float*)out)[(size_t)b * sO + (size_t)gr * 512 + gc] = v;
        } else {
          ((u16*)out)[(size_t)b * sO + (size_t)gr * 512 + gc] = f2bf(v);
        }
      }
    }
  }
}

// ---------------- scores + softmax -> P (bf16) ----------------
// Block: 32 q-rows x all 512 keys. 4 waves: wave = (rowgroup<<1)|keyhalf.
__global__ __launch_bounds__(256) void scores_softmax_k(const u16* __restrict__ Q,
                                                        const u16* __restrict__ K,
                                                        u16* __restrict__ P) {
  __shared__ u16 As[32 * 32];
  __shared__ u16 Bs[512 * 32];
  __shared__ float redmax[2][32], redsum[2][32];
  const int b = blockIdx.y;
  const int m0 = blockIdx.x * 32;
  const u16* Qb = Q + (size_t)b * 262144;
  const u16* Kb = K + (size_t)b * 262144;
  u16* Pb = P + (size_t)b * 262144;
  const int tid = threadIdx.x, w = tid >> 6, lane = tid & 63;
  const int rg = w >> 1;   // row group (16 rows)
  const int kh = w & 1;    // key half (256 keys)
  f32x4 acc[16] = {};
  const int srow = lane >> 2, scol = (lane & 3) * 8;

  for (int k0 = 0; k0 < 512; k0 += 32) {
#pragma unroll
    for (int i = 0; i < 8; ++i) {
      const int ch = w + i * 4;                   // 0..31
      gload_lds16(Kb + (size_t)(ch * 16 + srow) * 512 + k0 + scol, Bs + ch * 512);
    }
    if (w < 2) {
      gload_lds16(Qb + (size_t)(m0 + w * 16 + srow) * 512 + k0 + scol, As + w * 512);
    }
    asm volatile("s_waitcnt vmcnt(0)" ::: "memory");
    __syncthreads();
    const int frow = lane & 15, fk = (lane >> 4) * 8;
    short8 aq = *reinterpret_cast<const short8*>(&As[(rg * 16 + frow) * 32 + fk]);
#pragma unroll
    for (int f = 0; f < 16; ++f) {
      short8 bk = *reinterpret_cast<const short8*>(&Bs[(kh * 256 + f * 16 + frow) * 32 + fk]);
      acc[f] = __builtin_amdgcn_mfma_f32_16x16x32_bf16(aq, bk, acc[f], 0, 0, 0);
    }
    __syncthreads();
  }

  // scale + partial row max (per lane: rows (lane>>4)*4+r over its 16 cols/frag)
  float pm[4] = {-1e30f, -1e30f, -1e30f, -1e30f};
#pragma unroll
  for (int f = 0; f < 16; ++f)
#pragma unroll
    for (int r = 0; r < 4; ++r) {
      float v = acc[f][r] * SM_SCALE;
      acc[f][r] = v;
      pm[r] = fmaxf(pm[r], v);
    }
#pragma unroll
  for (int off = 1; off < 16; off <<= 1)
#pragma unroll
    for (int r = 0; r < 4; ++r) pm[r] = fmaxf(pm[r], __shfl_xor(pm[r], off));
  if ((lane & 15) == 0) {
#pragma unroll
    for (int r = 0; r < 4; ++r) redmax[kh][rg * 16 + (lane >> 4) * 4 + r] = pm[r];
  }
  __syncthreads();
  float rowm[4];
#pragma unroll
  for (int r = 0; r < 4; ++r) {
    const int rr = rg * 16 + (lane >> 4) * 4 + r;
    rowm[r] = fmaxf(redmax[0][rr], redmax[1][rr]);
  }
  float ps[4] = {0.f, 0.f, 0.f, 0.f};
#pragma unroll
  for (int f = 0; f < 16; ++f)
#pragma unroll
    for (int r = 0; r < 4; ++r) {
      float e = __expf(acc[f][r] - rowm[r]);
      acc[f][r] = e;
      ps[r] += e;
    }
#pragma unroll
  for (int off = 1; off < 16; off <<= 1)
#pragma unroll
    for (int r = 0; r < 4; ++r) ps[r] += __shfl_xor(ps[r], off);
  if ((lane & 15) == 0) {
#pragma unroll
    for (int r = 0; r < 4; ++r) redsum[kh][rg * 16 + (lane >> 4) * 4 + r] = ps[r];
  }
  __syncthreads();
  float rinv[4];
#pragma unroll
  for (int r = 0; r < 4; ++r) {
    const int rr = rg * 16 + (lane >> 4) * 4 + r;
    rinv[r] = 1.0f / (redsum[0][rr] + redsum[1][rr]);
  }
#pragma unroll
  for (int f = 0; f < 16; ++f) {
    const int gcol = kh * 256 + f * 16 + (lane & 15);
#pragma unroll
    for (int r = 0; r < 4; ++r) {
      const int grow = m0 + rg * 16 + (lane >> 4) * 4 + r;
      Pb[(size_t)grow * 512 + gcol] = f2bf(acc[f][r] * rinv[r]);
    }
  }
}

extern "C" void kernel_launch(void* const* d_in, const int* in_sizes, int n_in,
                              void* d_out, int out_size, void* d_ws, size_t ws_size,
                              hipStream_t stream) {
  const float* x = (const float*)d_in[0];
  const float* qw = (const float*)d_in[1];
  const float* qb = (const float*)d_in[2];
  const float* kw = (const float*)d_in[3];
  const float* kb = (const float*)d_in[4];
  const float* vw = (const float*)d_in[5];
  const float* vb = (const float*)d_in[6];
  const float* gnw = (const float*)d_in[7];
  const float* gnb = (const float*)d_in[8];

  char* ws = (char*)d_ws;
  float* stats = (float*)(ws);                         // 16 KB
  u16* qwb = (u16*)(ws + 16384);                       // 512 KB
  u16* kwb = (u16*)(ws + 16384 + 524288);
  u16* vwb = (u16*)(ws + 16384 + 2 * 524288);
  u16* xn = (u16*)(ws + 16384 + 3 * 524288);           // 33.5 MB (reused for P)
  u16* Qb = xn + 16777216;
  u16* Kb = Qb + 16777216;
  u16* VT = Kb + 16777216;
  u16* P = xn;                                          // alias: xn dead after QKV GEMMs
  float* out = (float*)d_out;

  gn_stats_k<<<dim3(2048), dim3(256), 0, stream>>>(x, stats);
  cast_bf_k<<<dim3(128), dim3(256), 0, stream>>>(qw, qwb);
  cast_bf_k<<<dim3(128), dim3(256), 0, stream>>>(kw, kwb);
  cast_bf_k<<<dim3(128), dim3(256), 0, stream>>>(vw, vwb);
  gn_apply_k<<<dim3(8192), dim3(256), 0, stream>>>(x, stats, gnw, gnb, xn);

  // Q = xn * qw^T + qb ; K = xn * kw^T + kb   (bf16 out, col bias)
  gemm_abt_k<0><<<dim3(16, 64), dim3(256), 0, stream>>>(xn, (size_t)262144, qwb, (size_t)0, qb, (void*)Qb, (size_t)262144);
  gemm_abt_k<0><<<dim3(16, 64), dim3(256), 0, stream>>>(xn, (size_t)262144, kwb, (size_t)0, kb, (void*)Kb, (size_t)262144);
  // V^T = vw * xn^T + vb  (bf16 out, row bias)
  gemm_abt_k<1><<<dim3(16, 64), dim3(256), 0, stream>>>(vwb, (size_t)0, xn, (size_t)262144, vb, (void*)VT, (size_t)262144);

  // P = softmax(Q K^T / sqrt(512))  (bf16, overwrites xn)
  scores_softmax_k<<<dim3(16, 64), dim3(256), 0, stream>>>(Qb, Kb, P);

  // out = P * V = P * (V^T)^T  (f32)
  gemm_abt_k<2><<<dim3(16, 64), dim3(256), 0, stream>>>(P, (size_t)262144, VT, (size_t)262144, (const float*)nullptr, (void*)out, (size_t)262144);
}

// Round 3
// 182.995 us; speedup vs baseline: 1.3017x; 1.3017x over previous
//
#include <hip/hip_runtime.h>
#include <cstdint>

#define EPSV 1e-5f
#define SM_SCALE 0.044194173824159216f

typedef unsigned short u16;
typedef __attribute__((ext_vector_type(8))) short short8;
typedef __attribute__((ext_vector_type(4))) float f32x4;

__device__ __forceinline__ u16 f2bf(float f) {
  union { float f; uint32_t u; } v; v.f = f;
  return (u16)((v.u + 0x7FFFu + ((v.u >> 16) & 1u)) >> 16);
}

__device__ __forceinline__ void gload_lds16(const void* g, void* l) {
  __builtin_amdgcn_global_load_lds((const __attribute__((address_space(1))) void*)g,
                                   (__attribute__((address_space(3))) void*)l, 16, 0, 0);
}

// ---------- Fused GroupNorm (stats + apply in one pass via LDS) ----------
// One block per (b, group): 16 ch x 512 = 8192 floats = 32 KB LDS.
__global__ __launch_bounds__(256) void gn_fused_k(const float* __restrict__ x,
                                                  const float* __restrict__ gw,
                                                  const float* __restrict__ gb,
                                                  u16* __restrict__ xn) {
  __shared__ float xs[8192];
  __shared__ float ls[4], lss[4];
  const int bg = blockIdx.x;                     // 0..2047
  const int g = bg & 31;                         // group
  const float* p = x + (size_t)bg * 8192;
  float s = 0.f, ss = 0.f;
#pragma unroll
  for (int i = 0; i < 8; ++i) {
    const int idx = i * 1024 + threadIdx.x * 4;
    float4 v = *reinterpret_cast<const float4*>(p + idx);
    *reinterpret_cast<float4*>(xs + idx) = v;
    s += v.x + v.y + v.z + v.w;
    ss += v.x * v.x + v.y * v.y + v.z * v.z + v.w * v.w;
  }
  for (int off = 32; off; off >>= 1) { s += __shfl_xor(s, off); ss += __shfl_xor(ss, off); }
  const int w = threadIdx.x >> 6;
  if ((threadIdx.x & 63) == 0) { ls[w] = s; lss[w] = ss; }
  __syncthreads();
  s = ls[0] + ls[1] + ls[2] + ls[3];
  ss = lss[0] + lss[1] + lss[2] + lss[3];
  const float inv_n = 1.0f / 8192.f;
  const float mean = s * inv_n;
  const float rstd = rsqrtf(ss * inv_n - mean * mean + EPSV);
#pragma unroll
  for (int j = 0; j < 4; ++j) {
    const int idx = j * 2048 + threadIdx.x * 8;
    const int c = g * 16 + (idx >> 9);           // wave-uniform
    const float sc = gw[c] * rstd;
    const float sh = gb[c] - mean * sc;
    u16 o[8];
#pragma unroll
    for (int e = 0; e < 8; ++e) o[e] = f2bf(xs[idx + e] * sc + sh);
    *reinterpret_cast<uint4*>(xn + (size_t)bg * 8192 + idx) = *reinterpret_cast<const uint4*>(o);
  }
}

// ---------- fp32 -> bf16 cast for the 3 weight matrices, one launch ----------
__global__ __launch_bounds__(256) void cast3_k(const float* __restrict__ a,
                                               const float* __restrict__ b2,
                                               const float* __restrict__ c,
                                               u16* __restrict__ oa, u16* __restrict__ ob,
                                               u16* __restrict__ oc) {
  const int which = blockIdx.x >> 7;
  const float* in = which == 0 ? a : (which == 1 ? b2 : c);
  u16* out = which == 0 ? oa : (which == 1 ? ob : oc);
  size_t base = (((size_t)(blockIdx.x & 127)) * 256 + threadIdx.x) * 8;
  float4 v0 = *reinterpret_cast<const float4*>(in + base);
  float4 v1 = *reinterpret_cast<const float4*>(in + base + 4);
  u16 o[8];
  o[0] = f2bf(v0.x); o[1] = f2bf(v0.y); o[2] = f2bf(v0.z); o[3] = f2bf(v0.w);
  o[4] = f2bf(v1.x); o[5] = f2bf(v1.y); o[6] = f2bf(v1.z); o[7] = f2bf(v1.w);
  *reinterpret_cast<uint4*>(out + base) = *reinterpret_cast<const uint4*>(o);
}

// ---------- Batched GEMM: out[m,n] = sum_k A[m,k]*B[n,k] (+bias) ----------
// 1D grid of 1024 with XCD-bijective swizzle: all 16 tiles of a batch on one XCD.
// OUT_MODE: 0 = bf16 out, bias[col]; 1 = bf16 out, bias[row]; 2 = f32 out, no bias
template <int OUT_MODE>
__global__ __launch_bounds__(256) void gemm_abt_k(const u16* __restrict__ A, size_t sA,
                                                  const u16* __restrict__ Bm, size_t sB,
                                                  const float* __restrict__ bias,
                                                  void* __restrict__ out, size_t sO) {
  __shared__ u16 As[128 * 32];
  __shared__ u16 Bs[128 * 32];
  const int d = blockIdx.x;
  const int t = d >> 3;
  const int b = (d & 7) * 8 + (t >> 4);          // batch: same (d&7) => same XCD
  const int tile = t & 15;
  const u16* Ab = A + (size_t)b * sA;
  const u16* Bb = Bm + (size_t)b * sB;
  const int tm = (tile >> 2) * 128, tn = (tile & 3) * 128;
  const int tid = threadIdx.x;
  const int w = tid >> 6, lane = tid & 63;
  const int wr = (w >> 1) * 64, wc = (w & 1) * 64;

  f32x4 acc[4][4] = {};
  const int srow = lane >> 2;
  const int scol = (lane & 3) * 8;

  for (int k0 = 0; k0 < 512; k0 += 32) {
#pragma unroll
    for (int i = 0; i < 2; ++i) {
      const int ch = w + i * 4;
      gload_lds16(Ab + (size_t)(tm + ch * 16 + srow) * 512 + k0 + scol, As + ch * 512);
      gload_lds16(Bb + (size_t)(tn + ch * 16 + srow) * 512 + k0 + scol, Bs + ch * 512);
    }
    asm volatile("s_waitcnt vmcnt(0)" ::: "memory");
    __syncthreads();
    const int frow = lane & 15;
    const int fk = (lane >> 4) * 8;
    short8 af[4], bf[4];
#pragma unroll
    for (int i = 0; i < 4; ++i) {
      af[i] = *reinterpret_cast<const short8*>(&As[(wr + i * 16 + frow) * 32 + fk]);
      bf[i] = *reinterpret_cast<const short8*>(&Bs[(wc + i * 16 + frow) * 32 + fk]);
    }
#pragma unroll
    for (int mi = 0; mi < 4; ++mi)
#pragma unroll
      for (int ni = 0; ni < 4; ++ni)
        acc[mi][ni] = __builtin_amdgcn_mfma_f32_16x16x32_bf16(af[mi], bf[ni], acc[mi][ni], 0, 0, 0);
    __syncthreads();
  }

  const int col0 = lane & 15, row0 = (lane >> 4) * 4;
#pragma unroll
  for (int mi = 0; mi < 4; ++mi) {
#pragma unroll
    for (int ni = 0; ni < 4; ++ni) {
      const int gc = tn + wc + ni * 16 + col0;
#pragma unroll
      for (int r = 0; r < 4; ++r) {
        const int gr = tm + wr + mi * 16 + row0 + r;
        float v = acc[mi][ni][r];
        if (OUT_MODE == 0) v += bias[gc];
        if (OUT_MODE == 1) v += bias[gr];
        if (OUT_MODE == 2) {
          ((float*)out)[(size_t)b * sO + (size_t)gr * 512 + gc] = v;
        } else {
          ((u16*)out)[(size_t)b * sO + (size_t)gr * 512 + gc] = f2bf(v);
        }
      }
    }
  }
}

// ---------- scores + softmax -> P (bf16) ----------
// QBLK=128, 8 waves; wave w owns q-rows m0+w*16 .. +15 across ALL 512 keys.
// Full score row lives in registers (32 f32x4/lane); softmax is wave-local.
// 1D grid of 256 with XCD-bijective swizzle (4 q-tiles of a batch share an XCD's K).
__global__ __launch_bounds__(512) void scores_softmax_k(const u16* __restrict__ Q,
                                                        const u16* __restrict__ K,
                                                        u16* __restrict__ P) {
  __shared__ u16 Qs[128 * 32];
  __shared__ u16 Ks[512 * 32];
  const int d = blockIdx.x;                      // 0..255
  const int t = d >> 3;
  const int b = (d & 7) * 8 + (t >> 2);
  const int m0 = (t & 3) * 128;
  const u16* Qb = Q + (size_t)b * 262144 + (size_t)m0 * 512;
  const u16* Kb = K + (size_t)b * 262144;
  u16* Pb = P + (size_t)b * 262144;
  const int tid = threadIdx.x, w = tid >> 6, lane = tid & 63;
  f32x4 acc[32] = {};
  const int srow = lane >> 2, scol = (lane & 3) * 8;

  for (int k0 = 0; k0 < 512; k0 += 32) {
#pragma unroll
    for (int i = 0; i < 4; ++i) {
      const int ch = w + i * 8;                  // K chunks 0..31 over 8 waves
      gload_lds16(Kb + (size_t)(ch * 16 + srow) * 512 + k0 + scol, Ks + ch * 512);
    }
    gload_lds16(Qb + (size_t)(w * 16 + srow) * 512 + k0 + scol, Qs + w * 512);
    asm volatile("s_waitcnt vmcnt(0)" ::: "memory");
    __syncthreads();
    const int frow = lane & 15, fk = (lane >> 4) * 8;
    short8 aq = *reinterpret_cast<const short8*>(&Qs[(w * 16 + frow) * 32 + fk]);
#pragma unroll
    for (int f = 0; f < 32; ++f) {
      short8 bk = *reinterpret_cast<const short8*>(&Ks[(f * 16 + frow) * 32 + fk]);
      acc[f] = __builtin_amdgcn_mfma_f32_16x16x32_bf16(aq, bk, acc[f], 0, 0, 0);
    }
    __syncthreads();
  }

  // wave-local softmax: lane holds rows (lane>>4)*4+r, cols f*16+(lane&15)
  float pm[4] = {-1e30f, -1e30f, -1e30f, -1e30f};
#pragma unroll
  for (int f = 0; f < 32; ++f)
#pragma unroll
    for (int r = 0; r < 4; ++r) {
      float v = acc[f][r] * SM_SCALE;
      acc[f][r] = v;
      pm[r] = fmaxf(pm[r], v);
    }
#pragma unroll
  for (int off = 1; off < 16; off <<= 1)
#pragma unroll
    for (int r = 0; r < 4; ++r) pm[r] = fmaxf(pm[r], __shfl_xor(pm[r], off));
  float ps[4] = {0.f, 0.f, 0.f, 0.f};
#pragma unroll
  for (int f = 0; f < 32; ++f)
#pragma unroll
    for (int r = 0; r < 4; ++r) {
      float e = __expf(acc[f][r] - pm[r]);
      acc[f][r] = e;
      ps[r] += e;
    }
#pragma unroll
  for (int off = 1; off < 16; off <<= 1)
#pragma unroll
    for (int r = 0; r < 4; ++r) ps[r] += __shfl_xor(ps[r], off);
  float rinv[4];
#pragma unroll
  for (int r = 0; r < 4; ++r) rinv[r] = 1.0f / ps[r];
#pragma unroll
  for (int f = 0; f < 32; ++f) {
    const int gcol = f * 16 + (lane & 15);
#pragma unroll
    for (int r = 0; r < 4; ++r) {
      const int grow = m0 + w * 16 + (lane >> 4) * 4 + r;
      Pb[(size_t)grow * 512 + gcol] = f2bf(acc[f][r] * rinv[r]);
    }
  }
}

extern "C" void kernel_launch(void* const* d_in, const int* in_sizes, int n_in,
                              void* d_out, int out_size, void* d_ws, size_t ws_size,
                              hipStream_t stream) {
  const float* x = (const float*)d_in[0];
  const float* qw = (const float*)d_in[1];
  const float* qb = (const float*)d_in[2];
  const float* kw = (const float*)d_in[3];
  const float* kb = (const float*)d_in[4];
  const float* vw = (const float*)d_in[5];
  const float* vb = (const float*)d_in[6];
  const float* gnw = (const float*)d_in[7];
  const float* gnb = (const float*)d_in[8];

  char* ws = (char*)d_ws;
  u16* qwb = (u16*)(ws);                               // 512 KB each
  u16* kwb = (u16*)(ws + 524288);
  u16* vwb = (u16*)(ws + 2 * 524288);
  u16* xn = (u16*)(ws + 4 * 524288);                   // 32 MB (reused for P)
  u16* Qb = xn + 16777216;
  u16* Kb = Qb + 16777216;
  u16* VT = Kb + 16777216;
  u16* P = xn;                                          // xn dead after QKV GEMMs
  float* out = (float*)d_out;

  gn_fused_k<<<dim3(2048), dim3(256), 0, stream>>>(x, gnw, gnb, xn);
  cast3_k<<<dim3(384), dim3(256), 0, stream>>>(qw, kw, vw, qwb, kwb, vwb);

  // Q = xn * qw^T + qb ; K = xn * kw^T + kb   (bf16 out, col bias)
  gemm_abt_k<0><<<dim3(1024), dim3(256), 0, stream>>>(xn, (size_t)262144, qwb, (size_t)0, qb, (void*)Qb, (size_t)262144);
  gemm_abt_k<0><<<dim3(1024), dim3(256), 0, stream>>>(xn, (size_t)262144, kwb, (size_t)0, kb, (void*)Kb, (size_t)262144);
  // V^T = vw * xn^T + vb  (bf16 out, row bias)
  gemm_abt_k<1><<<dim3(1024), dim3(256), 0, stream>>>(vwb, (size_t)0, xn, (size_t)262144, vb, (void*)VT, (size_t)262144);

  // P = softmax(Q K^T / sqrt(512))  (bf16, overwrites xn)
  scores_softmax_k<<<dim3(256), dim3(512), 0, stream>>>(Qb, Kb, P);

  // out = P * V = P * (V^T)^T  (f32)
  gemm_abt_k<2><<<dim3(1024), dim3(256), 0, stream>>>(P, (size_t)262144, VT, (size_t)262144, (const float*)nullptr, (void*)out, (size_t)262144);
}